// Round 1
// baseline (56.658 us; speedup 1.0000x reference)
//
#include <hip/hip_runtime.h>
#include <hip/hip_bf16.h>

typedef __attribute__((ext_vector_type(8))) short bf16x8;
typedef __attribute__((ext_vector_type(4))) float f32x4;

__device__ __forceinline__ unsigned short f2bf(float f) {
    unsigned u = __builtin_bit_cast(unsigned, f);
    unsigned rnd = 0x7FFFu + ((u >> 16) & 1u);
    return (unsigned short)((u + rnd) >> 16);
}

// ---------------------------------------------------------------------------
// Setup: simulate the circuit on the 256 basis vectors -> U (256x256),
// write it into d_ws as pre-packed bf16 MFMA B-fragments.
// One wave per column k. Lane l holds amplitudes a = 4l + r (r = 0..3).
// Amp index bits: bit(7-q) = wire q. Lane bits = a[7:2], reg bits = a[1:0].
// ---------------------------------------------------------------------------
__global__ __launch_bounds__(256) void qnn_setup(const float* __restrict__ wts,
                                                 unsigned short* __restrict__ Bp) {
    __shared__ float cs[56], sn[56];
    int tid = threadIdx.x;
    if (tid < 56) {
        float th = 0.5f * wts[tid];
        cs[tid] = cosf(th);
        sn[tid] = sinf(th);
    }
    __syncthreads();

    int l = tid & 63;
    int k = blockIdx.x * 4 + (tid >> 6);   // column 0..255
    int a0 = l << 2;

    float v0 = (float)(a0 + 0 == k);
    float v1 = (float)(a0 + 1 == k);
    float v2 = (float)(a0 + 2 == k);
    float v3 = (float)(a0 + 3 == k);

#pragma unroll
    for (int L = 0; L < 7; ++L) {
        // RY wires q=0..5 : amp bit b = 7-q >= 2 -> lane bit m = 5-q
#pragma unroll
        for (int q = 0; q <= 5; ++q) {
            int m = 5 - q;
            float c = cs[L * 8 + q], s = sn[L * 8 + q];
            float ss = ((l >> m) & 1) ? s : -s;
            float p0 = __shfl_xor(v0, 1 << m);
            float p1 = __shfl_xor(v1, 1 << m);
            float p2 = __shfl_xor(v2, 1 << m);
            float p3 = __shfl_xor(v3, 1 << m);
            v0 = fmaf(ss, p0, c * v0);
            v1 = fmaf(ss, p1, c * v1);
            v2 = fmaf(ss, p2, c * v2);
            v3 = fmaf(ss, p3, c * v3);
        }
        {   // RY wire 6 : amp bit 1 -> pairs (v0,v2),(v1,v3)
            float c = cs[L * 8 + 6], s = sn[L * 8 + 6];
            float n0 = fmaf(-s, v2, c * v0), n2 = fmaf(s, v0, c * v2);
            float n1 = fmaf(-s, v3, c * v1), n3 = fmaf(s, v1, c * v3);
            v0 = n0; v1 = n1; v2 = n2; v3 = n3;
        }
        {   // RY wire 7 : amp bit 0 -> pairs (v0,v1),(v2,v3)
            float c = cs[L * 8 + 7], s = sn[L * 8 + 7];
            float n0 = fmaf(-s, v1, c * v0), n1 = fmaf(s, v0, c * v1);
            float n2 = fmaf(-s, v3, c * v2), n3 = fmaf(s, v2, c * v3);
            v0 = n0; v1 = n1; v2 = n2; v3 = n3;
        }
        // CNOTs q=0..4 (ctl bit 7-q, tgt bit 6-q, both lane bits):
        // new[i] = old[g0(g1(g2(g3(g4(i)))))], g_q(x) = x ^ (((x>>(5-q))&1)<<(4-q))
        {
            int src = l;
#pragma unroll
            for (int q = 4; q >= 0; --q)
                src = src ^ (((src >> (5 - q)) & 1) << (4 - q));
            v0 = __shfl(v0, src);
            v1 = __shfl(v1, src);
            v2 = __shfl(v2, src);
            v3 = __shfl(v3, src);
        }
        {   // CNOT q=5: ctl = lane bit0, tgt = reg bit1 -> odd lanes swap (v0,v2),(v1,v3)
            bool cc = (l & 1);
            float n0 = cc ? v2 : v0, n2 = cc ? v0 : v2;
            float n1 = cc ? v3 : v1, n3 = cc ? v1 : v3;
            v0 = n0; v1 = n1; v2 = n2; v3 = n3;
        }
        {   // CNOT q=6: ctl = reg bit1, tgt = reg bit0 -> swap v2,v3 (free rename)
            float t = v2; v2 = v3; v3 = t;
        }
    }

    // Pack U[n][k] (n = 4l + r) into B-fragments for mfma_f32_16x16x32_bf16:
    // frag (u = n>>4, t = k>>5); lane slot ls = ((k>>3)&3)*16 + (n&15); reg j = k&7.
    int t = k >> 5, j = k & 7, lk = (k >> 3) & 3;
#pragma unroll
    for (int r = 0; r < 4; ++r) {
        int n = a0 + r;
        int u = n >> 4;
        int ls = lk * 16 + (n & 15);
        float val = (r == 0) ? v0 : (r == 1) ? v1 : (r == 2) ? v2 : v3;
        Bp[(((u * 8 + t) * 64) + ls) * 8 + j] = f2bf(val);
    }
}

// ---------------------------------------------------------------------------
// Main: per block 128 samples. X -> bf16 LDS (swizzled), W = X * U^T via MFMA,
// z = (sum_n sign(n) W^2) / ||x||^2, then the tiny MLP + sigmoid.
// ---------------------------------------------------------------------------
__global__ __launch_bounds__(512, 4) void qnn_main(
    const float* __restrict__ x, const unsigned short* __restrict__ Bp,
    const float* __restrict__ W1, const float* __restrict__ b1,
    const float* __restrict__ W2, const float* __restrict__ b2,
    float* __restrict__ out) {
    __shared__ __align__(16) unsigned short Xs[128][256];
    __shared__ float norms[128];

    int tid = threadIdx.x;
    int l = tid & 63, w = tid >> 6;
    size_t base = (size_t)blockIdx.x * 128 * 256;

    // ---- Phase 1: load + convert + swizzled LDS store + per-sample norms ----
    int r = tid >> 2, qt = tid & 3;
    const float4* xr = (const float4*)(x + base + (size_t)r * 256 + qt * 64);
    float ssum = 0.f;
#pragma unroll
    for (int i = 0; i < 16; ++i) {
        float4 f = xr[i];
        ssum = fmaf(f.x, f.x, fmaf(f.y, f.y, fmaf(f.z, f.z, fmaf(f.w, f.w, ssum))));
        ushort4 h;
        h.x = f2bf(f.x); h.y = f2bf(f.y); h.z = f2bf(f.z); h.w = f2bf(f.w);
        int col = qt * 64 + i * 4;
        int chunk = col >> 3;                 // 16B chunk of 8 bf16
        int swz = chunk ^ (r & 7);            // T2-style XOR swizzle
        *(ushort4*)&Xs[r][swz * 8 + (col & 7)] = h;
    }
    ssum += __shfl_xor(ssum, 1);
    ssum += __shfl_xor(ssum, 2);
    if (qt == 0) norms[r] = ssum;
    __syncthreads();

    // ---- Phase 2: MFMA. Wave w owns sample rows 16w..16w+15, full N=256. ----
    f32x4 acc[16];
#pragma unroll
    for (int u = 0; u < 16; ++u) acc[u] = (f32x4){0.f, 0.f, 0.f, 0.f};

    int arow = 16 * w + (l & 15);
    int kg = l >> 4;
#pragma unroll
    for (int t = 0; t < 8; ++t) {
        int chunk = t * 4 + kg;
        bf16x8 af = *(const bf16x8*)&Xs[arow][(chunk ^ (arow & 7)) * 8];
        const unsigned short* bp = Bp + (size_t)(t * 64 + l) * 8;
#pragma unroll
        for (int u = 0; u < 16; ++u) {
            bf16x8 bfr = *(const bf16x8*)(bp + (size_t)u * 4096);
            acc[u] = __builtin_amdgcn_mfma_f32_16x16x32_bf16(af, bfr, acc[u], 0, 0, 0);
        }
    }

    // ---- Epilogue: q = sum_n sign(n) * w_n^2 (sign + for n<128 <=> u<8) ----
    float q[4] = {0.f, 0.f, 0.f, 0.f};
#pragma unroll
    for (int u = 0; u < 16; ++u) {
#pragma unroll
        for (int j = 0; j < 4; ++j) {
            float a = acc[u][j];
            q[j] = (u < 8) ? fmaf(a, a, q[j]) : fmaf(-a, a, q[j]);
        }
    }
#pragma unroll
    for (int d = 1; d < 16; d <<= 1) {
#pragma unroll
        for (int j = 0; j < 4; ++j) q[j] += __shfl_xor(q[j], d);
    }

    // C/D layout: col = lane&15, row = (lane>>4)*4 + reg (verified m89/m91)
    if ((l & 15) < 4) {
        int j = l & 3;
        int row = 16 * w + (l >> 4) * 4 + j;
        float z = q[j] / norms[row];
        float o = b2[0];
#pragma unroll
        for (int jj = 0; jj < 16; ++jj) {
            float h = fmaf(z, W1[jj], b1[jj]);
            h = h > 0.f ? h : 0.f;
            o = fmaf(W2[jj], h, o);
        }
        out[(size_t)blockIdx.x * 128 + row] = 1.f / (1.f + expf(-o));
    }
}

extern "C" void kernel_launch(void* const* d_in, const int* in_sizes, int n_in,
                              void* d_out, int out_size, void* d_ws, size_t ws_size,
                              hipStream_t stream) {
    const float* x   = (const float*)d_in[0];
    const float* wts = (const float*)d_in[1];
    const float* W1  = (const float*)d_in[2];
    const float* b1  = (const float*)d_in[3];
    const float* W2  = (const float*)d_in[4];
    const float* b2  = (const float*)d_in[5];
    float* out = (float*)d_out;
    unsigned short* Bp = (unsigned short*)d_ws;   // 65536 bf16 = 128 KB

    int B = in_sizes[0] >> 8;        // 65536 samples
    qnn_setup<<<64, 256, 0, stream>>>(wts, Bp);
    qnn_main<<<B / 128, 512, 0, stream>>>(x, Bp, W1, b1, W2, b2, out);
}

// Round 2
// 48.902 us; speedup vs baseline: 1.1586x; 1.1586x over previous
//
#include <hip/hip_runtime.h>
#include <hip/hip_bf16.h>

typedef __attribute__((ext_vector_type(8))) short bf16x8;
typedef __attribute__((ext_vector_type(4))) float f32x4;

__device__ __forceinline__ unsigned short f2bf(float f) {
    unsigned u = __builtin_bit_cast(unsigned, f);
    unsigned rnd = 0x7FFFu + ((u >> 16) & 1u);
    return (unsigned short)((u + rnd) >> 16);
}

// ---------------------------------------------------------------------------
// Setup: simulate the circuit on the 256 basis vectors -> U (256x256),
// write it into d_ws as pre-packed bf16 MFMA B-fragments.
// One wave per column k. Lane l holds amplitudes a = 4l + r (r = 0..3).
// Amp index bits: bit(7-q) = wire q. Lane bits = a[7:2], reg bits = a[1:0].
// ---------------------------------------------------------------------------
__global__ __launch_bounds__(256) void qnn_setup(const float* __restrict__ wts,
                                                 unsigned short* __restrict__ Bp) {
    __shared__ float cs[56], sn[56];
    int tid = threadIdx.x;
    if (tid < 56) {
        float th = 0.5f * wts[tid];
        cs[tid] = cosf(th);
        sn[tid] = sinf(th);
    }
    __syncthreads();

    int l = tid & 63;
    int k = blockIdx.x * 4 + (tid >> 6);   // column 0..255
    int a0 = l << 2;

    float v0 = (float)(a0 + 0 == k);
    float v1 = (float)(a0 + 1 == k);
    float v2 = (float)(a0 + 2 == k);
    float v3 = (float)(a0 + 3 == k);

#pragma unroll
    for (int L = 0; L < 7; ++L) {
        // RY wires q=0..5 : amp bit b = 7-q >= 2 -> lane bit m = 5-q
#pragma unroll
        for (int q = 0; q <= 5; ++q) {
            int m = 5 - q;
            float c = cs[L * 8 + q], s = sn[L * 8 + q];
            float ss = ((l >> m) & 1) ? s : -s;
            float p0 = __shfl_xor(v0, 1 << m);
            float p1 = __shfl_xor(v1, 1 << m);
            float p2 = __shfl_xor(v2, 1 << m);
            float p3 = __shfl_xor(v3, 1 << m);
            v0 = fmaf(ss, p0, c * v0);
            v1 = fmaf(ss, p1, c * v1);
            v2 = fmaf(ss, p2, c * v2);
            v3 = fmaf(ss, p3, c * v3);
        }
        {   // RY wire 6 : amp bit 1 -> pairs (v0,v2),(v1,v3)
            float c = cs[L * 8 + 6], s = sn[L * 8 + 6];
            float n0 = fmaf(-s, v2, c * v0), n2 = fmaf(s, v0, c * v2);
            float n1 = fmaf(-s, v3, c * v1), n3 = fmaf(s, v1, c * v3);
            v0 = n0; v1 = n1; v2 = n2; v3 = n3;
        }
        {   // RY wire 7 : amp bit 0 -> pairs (v0,v1),(v2,v3)
            float c = cs[L * 8 + 7], s = sn[L * 8 + 7];
            float n0 = fmaf(-s, v1, c * v0), n1 = fmaf(s, v0, c * v1);
            float n2 = fmaf(-s, v3, c * v2), n3 = fmaf(s, v2, c * v3);
            v0 = n0; v1 = n1; v2 = n2; v3 = n3;
        }
        // CNOTs q=0..4 (ctl bit 7-q, tgt bit 6-q, both lane bits):
        // new[i] = old[g0(g1(g2(g3(g4(i)))))], g_q(x) = x ^ (((x>>(5-q))&1)<<(4-q))
        {
            int src = l;
#pragma unroll
            for (int q = 4; q >= 0; --q)
                src = src ^ (((src >> (5 - q)) & 1) << (4 - q));
            v0 = __shfl(v0, src);
            v1 = __shfl(v1, src);
            v2 = __shfl(v2, src);
            v3 = __shfl(v3, src);
        }
        {   // CNOT q=5: ctl = lane bit0, tgt = reg bit1 -> odd lanes swap (v0,v2),(v1,v3)
            bool cc = (l & 1);
            float n0 = cc ? v2 : v0, n2 = cc ? v0 : v2;
            float n1 = cc ? v3 : v1, n3 = cc ? v1 : v3;
            v0 = n0; v1 = n1; v2 = n2; v3 = n3;
        }
        {   // CNOT q=6: ctl = reg bit1, tgt = reg bit0 -> swap v2,v3 (free rename)
            float t = v2; v2 = v3; v3 = t;
        }
    }

    // Pack U[n][k] (n = 4l + r) into B-fragments for mfma_f32_16x16x32_bf16:
    // frag (u = n>>4, t = k>>5); lane slot ls = ((k>>3)&3)*16 + (n&15); reg j = k&7.
    int t = k >> 5, j = k & 7, lk = (k >> 3) & 3;
#pragma unroll
    for (int r = 0; r < 4; ++r) {
        int n = a0 + r;
        int u = n >> 4;
        int ls = lk * 16 + (n & 15);
        float val = (r == 0) ? v0 : (r == 1) ? v1 : (r == 2) ? v2 : v3;
        Bp[(((u * 8 + t) * 64) + ls) * 8 + j] = f2bf(val);
    }
}

// ---------------------------------------------------------------------------
// Main: per block 128 samples; wave w owns samples 16w..16w+15 end-to-end
// (its own LDS rows -> no __syncthreads). u-outer loop keeps ONE f32x4
// accumulator pair live (R1 fix: no register spill).
// ---------------------------------------------------------------------------
__global__ __launch_bounds__(512, 2) void qnn_main(
    const float* __restrict__ x, const unsigned short* __restrict__ Bp,
    const float* __restrict__ W1, const float* __restrict__ b1,
    const float* __restrict__ W2, const float* __restrict__ b2,
    float* __restrict__ out) {
    __shared__ __align__(16) unsigned short Xs[128][256];   // 64 KB
    __shared__ float norms[128];

    int tid = threadIdx.x;
    int l = tid & 63, w = tid >> 6;
    size_t base = (size_t)blockIdx.x * 128 * 256;

    // ---- Phase 1: wave w stages its 16 rows, coalesced 1 KB/instr ----
    // lane l covers cols 4l..4l+3; swizzle: 16B-chunk c -> c ^ (row&7)
#pragma unroll
    for (int i = 0; i < 16; ++i) {
        int row = 16 * w + i;
        float4 f = *(const float4*)(x + base + (size_t)row * 256 + 4 * l);
        float ssum = fmaf(f.x, f.x, fmaf(f.y, f.y, fmaf(f.z, f.z, f.w * f.w)));
#pragma unroll
        for (int d = 1; d < 64; d <<= 1) ssum += __shfl_xor(ssum, d);
        if (l == 0) norms[row] = ssum;
        ushort4 h;
        h.x = f2bf(f.x); h.y = f2bf(f.y); h.z = f2bf(f.z); h.w = f2bf(f.w);
        int swz = (l >> 1) ^ (row & 7);
        *(ushort4*)&Xs[row][swz * 8 + (l & 1) * 4] = h;
    }
    // no __syncthreads: each wave reads only the rows it wrote

    // ---- Phase 2: preload the 8 A-fragments (reused by all 16 u) ----
    int arow = 16 * w + (l & 15);
    int kg = l >> 4;
    bf16x8 af[8];
#pragma unroll
    for (int t = 0; t < 8; ++t) {
        int chunk = t * 4 + kg;
        af[t] = *(const bf16x8*)&Xs[arow][(chunk ^ (arow & 7)) * 8];
    }

    // ---- u-outer MFMA: one acc pair live; q = sum_n sign(n) * w_n^2 ----
    float q[4] = {0.f, 0.f, 0.f, 0.f};
    const unsigned short* bpl = Bp + (size_t)l * 8;
#pragma unroll
    for (int u = 0; u < 16; u += 2) {
        f32x4 a0 = {0.f, 0.f, 0.f, 0.f};
        f32x4 a1 = {0.f, 0.f, 0.f, 0.f};
        const unsigned short* b0 = bpl + (size_t)u * 4096;
        const unsigned short* b1p = bpl + (size_t)(u + 1) * 4096;
#pragma unroll
        for (int t = 0; t < 8; ++t) {
            a0 = __builtin_amdgcn_mfma_f32_16x16x32_bf16(
                af[t], *(const bf16x8*)(b0 + t * 512), a0, 0, 0, 0);
            a1 = __builtin_amdgcn_mfma_f32_16x16x32_bf16(
                af[t], *(const bf16x8*)(b1p + t * 512), a1, 0, 0, 0);
        }
        float sgn = (u < 8) ? 1.f : -1.f;   // n < 128 <=> u < 8
#pragma unroll
        for (int j = 0; j < 4; ++j) {
            q[j] = fmaf(sgn * a0[j], a0[j], q[j]);
            q[j] = fmaf(sgn * a1[j], a1[j], q[j]);
        }
    }
#pragma unroll
    for (int d = 1; d < 16; d <<= 1) {
#pragma unroll
        for (int j = 0; j < 4; ++j) q[j] += __shfl_xor(q[j], d);
    }

    // C/D layout: col = lane&15, row = (lane>>4)*4 + reg (verified m89/m91)
    if ((l & 15) < 4) {
        int j = l & 3;
        int row = 16 * w + (l >> 4) * 4 + j;
        float qv = (j == 0) ? q[0] : (j == 1) ? q[1] : (j == 2) ? q[2] : q[3];
        float z = qv / norms[row];
        float o = b2[0];
#pragma unroll
        for (int jj = 0; jj < 16; ++jj) {
            float h = fmaf(z, W1[jj], b1[jj]);
            h = h > 0.f ? h : 0.f;
            o = fmaf(W2[jj], h, o);
        }
        out[(size_t)blockIdx.x * 128 + row] = 1.f / (1.f + expf(-o));
    }
}

extern "C" void kernel_launch(void* const* d_in, const int* in_sizes, int n_in,
                              void* d_out, int out_size, void* d_ws, size_t ws_size,
                              hipStream_t stream) {
    const float* x   = (const float*)d_in[0];
    const float* wts = (const float*)d_in[1];
    const float* W1  = (const float*)d_in[2];
    const float* b1  = (const float*)d_in[3];
    const float* W2  = (const float*)d_in[4];
    const float* b2  = (const float*)d_in[5];
    float* out = (float*)d_out;
    unsigned short* Bp = (unsigned short*)d_ws;   // 65536 bf16 = 128 KB

    int B = in_sizes[0] >> 8;        // 65536 samples
    qnn_setup<<<64, 256, 0, stream>>>(wts, Bp);
    qnn_main<<<B / 128, 512, 0, stream>>>(x, Bp, W1, b1, W2, b2, out);
}

// Round 3
// 31.049 us; speedup vs baseline: 1.8248x; 1.5750x over previous
//
#include <hip/hip_runtime.h>
#include <hip/hip_bf16.h>

typedef __attribute__((ext_vector_type(8))) short bf16x8;
typedef __attribute__((ext_vector_type(4))) float f32x4;

__device__ __forceinline__ unsigned short f2bf(float f) {
    unsigned u = __builtin_bit_cast(unsigned, f);
    unsigned rnd = 0x7FFFu + ((u >> 16) & 1u);
    return (unsigned short)((u + rnd) >> 16);
}

// ---------------------------------------------------------------------------
// Setup: simulate the circuit on the 256 basis vectors -> U (256x256),
// write it into d_ws as pre-packed bf16 MFMA B-fragments.
// One wave per column k. Lane l holds amplitudes a = 4l + r (r = 0..3).
// ---------------------------------------------------------------------------
__global__ __launch_bounds__(256) void qnn_setup(const float* __restrict__ wts,
                                                 unsigned short* __restrict__ Bp) {
    __shared__ float cs[56], sn[56];
    int tid = threadIdx.x;
    if (tid < 56) {
        float th = 0.5f * wts[tid];
        cs[tid] = cosf(th);
        sn[tid] = sinf(th);
    }
    __syncthreads();

    int l = tid & 63;
    int k = blockIdx.x * 4 + (tid >> 6);   // column 0..255
    int a0 = l << 2;

    float v0 = (float)(a0 + 0 == k);
    float v1 = (float)(a0 + 1 == k);
    float v2 = (float)(a0 + 2 == k);
    float v3 = (float)(a0 + 3 == k);

#pragma unroll
    for (int L = 0; L < 7; ++L) {
#pragma unroll
        for (int q = 0; q <= 5; ++q) {     // RY wires 0..5 (lane bits)
            int m = 5 - q;
            float c = cs[L * 8 + q], s = sn[L * 8 + q];
            float ss = ((l >> m) & 1) ? s : -s;
            float p0 = __shfl_xor(v0, 1 << m);
            float p1 = __shfl_xor(v1, 1 << m);
            float p2 = __shfl_xor(v2, 1 << m);
            float p3 = __shfl_xor(v3, 1 << m);
            v0 = fmaf(ss, p0, c * v0);
            v1 = fmaf(ss, p1, c * v1);
            v2 = fmaf(ss, p2, c * v2);
            v3 = fmaf(ss, p3, c * v3);
        }
        {   // RY wire 6 (reg bit 1)
            float c = cs[L * 8 + 6], s = sn[L * 8 + 6];
            float n0 = fmaf(-s, v2, c * v0), n2 = fmaf(s, v0, c * v2);
            float n1 = fmaf(-s, v3, c * v1), n3 = fmaf(s, v1, c * v3);
            v0 = n0; v1 = n1; v2 = n2; v3 = n3;
        }
        {   // RY wire 7 (reg bit 0)
            float c = cs[L * 8 + 7], s = sn[L * 8 + 7];
            float n0 = fmaf(-s, v1, c * v0), n1 = fmaf(s, v0, c * v1);
            float n2 = fmaf(-s, v3, c * v2), n3 = fmaf(s, v2, c * v3);
            v0 = n0; v1 = n1; v2 = n2; v3 = n3;
        }
        {   // CNOTs q=0..4 (both bits in lane index): composed lane permute
            int src = l;
#pragma unroll
            for (int q = 4; q >= 0; --q)
                src = src ^ (((src >> (5 - q)) & 1) << (4 - q));
            v0 = __shfl(v0, src);
            v1 = __shfl(v1, src);
            v2 = __shfl(v2, src);
            v3 = __shfl(v3, src);
        }
        {   // CNOT q=5: ctl = lane bit0, tgt = reg bit1
            bool cc = (l & 1);
            float n0 = cc ? v2 : v0, n2 = cc ? v0 : v2;
            float n1 = cc ? v3 : v1, n3 = cc ? v1 : v3;
            v0 = n0; v1 = n1; v2 = n2; v3 = n3;
        }
        {   // CNOT q=6: swap v2,v3
            float t = v2; v2 = v3; v3 = t;
        }
    }

    // Pack U[n][k] into B-fragments for mfma_f32_16x16x32_bf16.
    int t = k >> 5, j = k & 7, lk = (k >> 3) & 3;
#pragma unroll
    for (int r = 0; r < 4; ++r) {
        int n = a0 + r;
        int u = n >> 4;
        int ls = lk * 16 + (n & 15);
        float val = (r == 0) ? v0 : (r == 1) ? v1 : (r == 2) ? v2 : v3;
        Bp[(((u * 8 + t) * 64) + ls) * 8 + j] = f2bf(val);
    }
}

// ---------------------------------------------------------------------------
// Main (R3): U staged ONCE per block into 128 KB LDS via global_load_lds,
// shared by all 8 waves (8x less global B traffic, LDS-latency reads).
// A-fragments loaded straight from global into registers (16 float4 in
// flight), norms via 2 shuffles. 4 independent MFMA chains per u-pair.
// ---------------------------------------------------------------------------
__global__ __launch_bounds__(512, 2) void qnn_main(
    const float* __restrict__ x, const unsigned short* __restrict__ Bp,
    const float* __restrict__ W1, const float* __restrict__ b1,
    const float* __restrict__ W2, const float* __restrict__ b2,
    float* __restrict__ out) {
    __shared__ __align__(16) unsigned short Blds[65536];   // 128 KB = all of U

    int tid = threadIdx.x;
    int l = tid & 63, w = tid >> 6;
    size_t base = (size_t)blockIdx.x * 128 * 256;

    // ---- Stage B: wave w copies bytes [w*16K, (w+1)*16K), 16B/lane/call ----
    {
        const unsigned short* src = Bp + w * 8192 + l * 8;
        unsigned short* dst = Blds + w * 8192;             // wave-uniform base
#pragma unroll
        for (int i = 0; i < 16; ++i) {
            __builtin_amdgcn_global_load_lds(
                (const __attribute__((address_space(1))) void*)(src + i * 512),
                (__attribute__((address_space(3))) void*)(dst + i * 512),
                16, 0, 0);
        }
    }

    // ---- A-fragments direct from global (hides under B staging) ----
    // lane l: row = 16w + (l&15), k-group kg = l>>4; frag t covers k=32t+8kg..+7
    const float* xrow = x + base + (size_t)(16 * w + (l & 15)) * 256 + (l >> 4) * 8;
    float4 fa[16];
#pragma unroll
    for (int t = 0; t < 8; ++t) {
        fa[2 * t]     = *(const float4*)(xrow + t * 32);
        fa[2 * t + 1] = *(const float4*)(xrow + t * 32 + 4);
    }
    float ss = 0.f;
    bf16x8 af[8];
#pragma unroll
    for (int t = 0; t < 8; ++t) {
        float4 f0 = fa[2 * t], f1 = fa[2 * t + 1];
        ss = fmaf(f0.x, f0.x, fmaf(f0.y, f0.y, fmaf(f0.z, f0.z, fmaf(f0.w, f0.w, ss))));
        ss = fmaf(f1.x, f1.x, fmaf(f1.y, f1.y, fmaf(f1.z, f1.z, fmaf(f1.w, f1.w, ss))));
        bf16x8 a;
        a[0] = (short)f2bf(f0.x); a[1] = (short)f2bf(f0.y);
        a[2] = (short)f2bf(f0.z); a[3] = (short)f2bf(f0.w);
        a[4] = (short)f2bf(f1.x); a[5] = (short)f2bf(f1.y);
        a[6] = (short)f2bf(f1.z); a[7] = (short)f2bf(f1.w);
        af[t] = a;
    }
    // row norm: combine the 4 k-groups of each row
    ss += __shfl_xor(ss, 16);
    ss += __shfl_xor(ss, 32);          // every lane now holds ||x_row||^2 of its row

    __syncthreads();                   // B staged (barrier drains vmcnt)

    // ---- u-outer MFMA from LDS: 4 independent chains of 4 ----
    float q[4] = {0.f, 0.f, 0.f, 0.f};
    const unsigned short* bl = &Blds[l * 8];
#pragma unroll
    for (int u = 0; u < 16; u += 2) {
        f32x4 a0e = {0.f, 0.f, 0.f, 0.f}, a0o = {0.f, 0.f, 0.f, 0.f};
        f32x4 a1e = {0.f, 0.f, 0.f, 0.f}, a1o = {0.f, 0.f, 0.f, 0.f};
#pragma unroll
        for (int t = 0; t < 4; ++t) {
            int g = u * 8 + 2 * t;
            bf16x8 b0e = *(const bf16x8*)(bl + (g    ) * 512);
            bf16x8 b0o = *(const bf16x8*)(bl + (g + 1) * 512);
            bf16x8 b1e = *(const bf16x8*)(bl + (g + 8) * 512);
            bf16x8 b1o = *(const bf16x8*)(bl + (g + 9) * 512);
            a0e = __builtin_amdgcn_mfma_f32_16x16x32_bf16(af[2 * t],     b0e, a0e, 0, 0, 0);
            a0o = __builtin_amdgcn_mfma_f32_16x16x32_bf16(af[2 * t + 1], b0o, a0o, 0, 0, 0);
            a1e = __builtin_amdgcn_mfma_f32_16x16x32_bf16(af[2 * t],     b1e, a1e, 0, 0, 0);
            a1o = __builtin_amdgcn_mfma_f32_16x16x32_bf16(af[2 * t + 1], b1o, a1o, 0, 0, 0);
        }
        float sgn = (u < 8) ? 1.f : -1.f;   // n < 128 <=> u < 8
#pragma unroll
        for (int j = 0; j < 4; ++j) {
            float w0 = a0e[j] + a0o[j];
            float w1 = a1e[j] + a1o[j];
            q[j] = fmaf(sgn * w0, w0, q[j]);
            q[j] = fmaf(sgn * w1, w1, q[j]);
        }
    }
#pragma unroll
    for (int d = 1; d < 16; d <<= 1) {
#pragma unroll
        for (int j = 0; j < 4; ++j) q[j] += __shfl_xor(q[j], d);
    }

    // norm for the row this lane will write (C/D: row=(l>>4)*4+j, col=l&15)
    float nrm = __shfl(ss, ((l >> 4) << 2) | (l & 3));

    if ((l & 15) < 4) {
        int j = l & 3;
        int row = 16 * w + (l >> 4) * 4 + j;
        float qv = (j == 0) ? q[0] : (j == 1) ? q[1] : (j == 2) ? q[2] : q[3];
        float z = qv / nrm;
        float o = b2[0];
#pragma unroll
        for (int jj = 0; jj < 16; ++jj) {
            float h = fmaf(z, W1[jj], b1[jj]);
            h = h > 0.f ? h : 0.f;
            o = fmaf(W2[jj], h, o);
        }
        out[(size_t)blockIdx.x * 128 + row] = 1.f / (1.f + expf(-o));
    }
}

extern "C" void kernel_launch(void* const* d_in, const int* in_sizes, int n_in,
                              void* d_out, int out_size, void* d_ws, size_t ws_size,
                              hipStream_t stream) {
    const float* x   = (const float*)d_in[0];
    const float* wts = (const float*)d_in[1];
    const float* W1  = (const float*)d_in[2];
    const float* b1  = (const float*)d_in[3];
    const float* W2  = (const float*)d_in[4];
    const float* b2  = (const float*)d_in[5];
    float* out = (float*)d_out;
    unsigned short* Bp = (unsigned short*)d_ws;   // 65536 bf16 = 128 KB

    int B = in_sizes[0] >> 8;        // 65536 samples
    qnn_setup<<<64, 256, 0, stream>>>(wts, Bp);
    qnn_main<<<B / 128, 512, 0, stream>>>(x, Bp, W1, b1, W2, b2, out);
}